// Round 1
// baseline (558.200 us; speedup 1.0000x reference)
//
#include <hip/hip_runtime.h>
#include <hip/hip_bf16.h>

#define NB 4
#define NC 256
#define NT 4096
#define NHEADS 4
#define DHD 64
#define NBH 16
#define NGROUPS 32
#define CPG 8
#define GN_EPS 1e-5f

typedef __attribute__((ext_vector_type(4))) float f32x4;
typedef __attribute__((ext_vector_type(8))) short s16x8;
typedef __attribute__((ext_vector_type(4))) short s16x4;

__device__ __forceinline__ unsigned short f2bf(float f) {
  union { float f; unsigned int u; } v; v.f = f;
  return (unsigned short)((v.u + 0x7fffu + ((v.u >> 16) & 1u)) >> 16);
}

// ---------------- kernel 0: convert weights to bf16 ----------------
__global__ __launch_bounds__(256) void k_cvt_w(const float* __restrict__ qkv_w,
                                               const float* __restrict__ proj_w,
                                               unsigned short* __restrict__ wq,
                                               unsigned short* __restrict__ wp) {
  int i = blockIdx.x * 256 + threadIdx.x;
  if (i < 768 * 256) wq[i] = f2bf(qkv_w[i]);
  if (i < 256 * 256) wp[i] = f2bf(proj_w[i]);
}

// ---------------- kernel 1: GroupNorm -> xnT[b][t][c] (bf16) ----------------
__global__ __launch_bounds__(256) void k_gn(const float* __restrict__ x,
                                            const float* __restrict__ gw,
                                            const float* __restrict__ gb,
                                            unsigned short* __restrict__ xnT) {
  int b = blockIdx.x >> 5;
  int g = blockIdx.x & 31;
  const float* xp = x + ((size_t)(b * NC + g * CPG)) * NT;  // 32768 contiguous floats
  int tid = threadIdx.x;
  float s = 0.f, ss = 0.f;
  const f32x4* xp4 = (const f32x4*)xp;
  for (int i = tid; i < (CPG * NT) / 4; i += 256) {
    f32x4 v = xp4[i];
    s += v.x + v.y + v.z + v.w;
    ss += v.x * v.x + v.y * v.y + v.z * v.z + v.w * v.w;
  }
#pragma unroll
  for (int off = 32; off > 0; off >>= 1) {
    s += __shfl_down(s, off);
    ss += __shfl_down(ss, off);
  }
  __shared__ float red[8];
  int w = tid >> 6;
  if ((tid & 63) == 0) { red[w * 2] = s; red[w * 2 + 1] = ss; }
  __syncthreads();
  float stot = red[0] + red[2] + red[4] + red[6];
  float sstot = red[1] + red[3] + red[5] + red[7];
  float mean = stot * (1.f / 32768.f);
  float var = sstot * (1.f / 32768.f) - mean * mean;
  float rstd = rsqrtf(var + GN_EPS);
  float sc[CPG], sh[CPG];
#pragma unroll
  for (int j = 0; j < CPG; ++j) {
    float gsc = rstd * gw[g * CPG + j];
    sc[j] = gsc;
    sh[j] = gb[g * CPG + j] - mean * gsc;
  }
  for (int t = tid; t < NT; t += 256) {
    s16x8 o;
#pragma unroll
    for (int j = 0; j < CPG; ++j)
      o[j] = (short)f2bf(fmaf(xp[(size_t)j * NT + t], sc[j], sh[j]));
    *(s16x8*)(xnT + ((size_t)b * NT + t) * NC + g * CPG) = o;
  }
}

// ---------------- kernel 2: QKV GEMM + scatter ----------------
// qT,kT: [bh][t][d] bf16 (q pre-scaled by 1/8); vS: [bh][d][t] bf16
__global__ __launch_bounds__(256) void k_qkv(const unsigned short* __restrict__ wq,
                                             const float* __restrict__ qkv_b,
                                             const unsigned short* __restrict__ xnT,
                                             unsigned short* __restrict__ qT,
                                             unsigned short* __restrict__ kT,
                                             unsigned short* __restrict__ vS) {
  int wid = blockIdx.x * 4 + (threadIdx.x >> 6);
  int lane = threadIdx.x & 63;
  int l15 = lane & 15, lg = lane >> 4;
  int b = wid / (48 * 256);
  int rem = wid - b * (48 * 256);
  int ot = rem >> 8, tt = rem & 255;
  f32x4 acc = {0.f, 0.f, 0.f, 0.f};
  const unsigned short* arow = wq + (size_t)(ot * 16 + l15) * NC;
  const unsigned short* brow = xnT + ((size_t)b * NT + tt * 16 + l15) * NC;
#pragma unroll
  for (int kk = 0; kk < 8; ++kk) {
    int c0 = kk * 32 + lg * 8;
    s16x8 af = *(const s16x8*)(arow + c0);
    s16x8 bf = *(const s16x8*)(brow + c0);
    acc = __builtin_amdgcn_mfma_f32_16x16x32_bf16(af, bf, acc, 0, 0, 0);
  }
  int o0 = ot * 16 + lg * 4;       // D row = 4*lg + r
  int t = tt * 16 + l15;           // D col = l15
  float r0 = acc[0] + qkv_b[o0 + 0];
  float r1 = acc[1] + qkv_b[o0 + 1];
  float r2 = acc[2] + qkv_b[o0 + 2];
  float r3 = acc[3] + qkv_b[o0 + 3];
  int which = o0 >> 8;
  int cc = o0 & 255;
  int h = cc >> 6, d0 = cc & 63;
  int bh = b * NHEADS + h;
  if (which == 0) {
    s16x4 pk = {(short)f2bf(r0 * 0.125f), (short)f2bf(r1 * 0.125f),
                (short)f2bf(r2 * 0.125f), (short)f2bf(r3 * 0.125f)};
    *(s16x4*)(qT + ((size_t)bh * NT + t) * DHD + d0) = pk;
  } else if (which == 1) {
    s16x4 pk = {(short)f2bf(r0), (short)f2bf(r1), (short)f2bf(r2), (short)f2bf(r3)};
    *(s16x4*)(kT + ((size_t)bh * NT + t) * DHD + d0) = pk;
  } else {
    vS[((size_t)bh * DHD + d0 + 0) * NT + t] = f2bf(r0);
    vS[((size_t)bh * DHD + d0 + 1) * NT + t] = f2bf(r1);
    vS[((size_t)bh * DHD + d0 + 2) * NT + t] = f2bf(r2);
    vS[((size_t)bh * DHD + d0 + 3) * NT + t] = f2bf(r3);
  }
}

// ---------------- kernel 3: flash attention ----------------
// one wave handles 32 q-rows; S^T = K*Q so D-layout col = tq; P^T D-frag feeds
// mfma_f32_16x16x16bf16_1k B-operand directly (K=16: k=4g+i == D row=4g+r).
__global__ __launch_bounds__(256) void k_attn(const unsigned short* __restrict__ qT,
                                              const unsigned short* __restrict__ kT,
                                              const unsigned short* __restrict__ vS,
                                              unsigned short* __restrict__ aT) {
  int wid = blockIdx.x * 4 + (threadIdx.x >> 6);
  int lane = threadIdx.x & 63;
  int l15 = lane & 15, lg = lane >> 4;
  int bh = wid >> 7;              // 128 waves per bh
  int tq0 = (wid & 127) << 5;     // 32 q-rows per wave
  s16x8 qf[2][2];
#pragma unroll
  for (int tt = 0; tt < 2; ++tt)
#pragma unroll
    for (int kk = 0; kk < 2; ++kk)
      qf[tt][kk] = *(const s16x8*)(qT + ((size_t)bh * NT + tq0 + tt * 16 + l15) * DHD + kk * 32 + lg * 8);
  f32x4 O[2][4];
#pragma unroll
  for (int tt = 0; tt < 2; ++tt)
#pragma unroll
    for (int d = 0; d < 4; ++d) O[tt][d] = (f32x4){0.f, 0.f, 0.f, 0.f};
  float mx[2] = {-1e30f, -1e30f};
  float ls[2] = {0.f, 0.f};
  for (int s0 = 0; s0 < NT; s0 += 16) {
    const unsigned short* krow = kT + ((size_t)bh * NT + s0 + l15) * DHD + lg * 8;
    s16x8 kf0 = *(const s16x8*)(krow);
    s16x8 kf1 = *(const s16x8*)(krow + 32);
    s16x4 vf[4];
#pragma unroll
    for (int dblk = 0; dblk < 4; ++dblk)
      vf[dblk] = *(const s16x4*)(vS + ((size_t)bh * DHD + dblk * 16 + l15) * NT + s0 + lg * 4);
#pragma unroll
    for (int tt = 0; tt < 2; ++tt) {
      f32x4 st = {0.f, 0.f, 0.f, 0.f};
      st = __builtin_amdgcn_mfma_f32_16x16x32_bf16(kf0, qf[tt][0], st, 0, 0, 0);
      st = __builtin_amdgcn_mfma_f32_16x16x32_bf16(kf1, qf[tt][1], st, 0, 0, 0);
      // st[r] = S^T[ts = s0+4*lg+r][tq = tq0+16*tt+l15]
      float tmax = fmaxf(fmaxf(st[0], st[1]), fmaxf(st[2], st[3]));
      tmax = fmaxf(tmax, __shfl_xor(tmax, 16));
      tmax = fmaxf(tmax, __shfl_xor(tmax, 32));
      float mn = fmaxf(mx[tt], tmax);
      float corr = __expf(mx[tt] - mn);
      mx[tt] = mn;
      float p0 = __expf(st[0] - mn);
      float p1 = __expf(st[1] - mn);
      float p2 = __expf(st[2] - mn);
      float p3 = __expf(st[3] - mn);
      float psum = p0 + p1 + p2 + p3;
      psum += __shfl_xor(psum, 16);
      psum += __shfl_xor(psum, 32);
      ls[tt] = ls[tt] * corr + psum;
      s16x4 pf = {(short)f2bf(p0), (short)f2bf(p1), (short)f2bf(p2), (short)f2bf(p3)};
#pragma unroll
      for (int dblk = 0; dblk < 4; ++dblk) {
        O[tt][dblk] = O[tt][dblk] * corr;
        O[tt][dblk] = __builtin_amdgcn_mfma_f32_16x16x16bf16_1k(vf[dblk], pf, O[tt][dblk], 0, 0, 0);
      }
    }
  }
  int b = bh >> 2, h = bh & 3;
#pragma unroll
  for (int tt = 0; tt < 2; ++tt) {
    float inv = 1.0f / ls[tt];
    int t = tq0 + tt * 16 + l15;
#pragma unroll
    for (int dblk = 0; dblk < 4; ++dblk) {
      s16x4 pk;
#pragma unroll
      for (int r = 0; r < 4; ++r) pk[r] = (short)f2bf(O[tt][dblk][r] * inv);
      *(s16x4*)(aT + ((size_t)b * NT + t) * NC + h * DHD + dblk * 16 + lg * 4) = pk;
    }
  }
}

// ---------------- kernel 4: proj GEMM + bias + residual ----------------
__global__ __launch_bounds__(256) void k_proj(const unsigned short* __restrict__ wp,
                                              const float* __restrict__ proj_b,
                                              const unsigned short* __restrict__ aT,
                                              const float* __restrict__ x,
                                              float* __restrict__ out) {
  int wid = blockIdx.x * 4 + (threadIdx.x >> 6);
  int lane = threadIdx.x & 63;
  int l15 = lane & 15, lg = lane >> 4;
  int b = wid / (16 * 256);
  int rem = wid - b * (16 * 256);
  int ot = rem >> 8, tt = rem & 255;
  f32x4 acc = {0.f, 0.f, 0.f, 0.f};
  const unsigned short* arow = wp + (size_t)(ot * 16 + l15) * NC;
  const unsigned short* brow = aT + ((size_t)b * NT + tt * 16 + l15) * NC;
#pragma unroll
  for (int kk = 0; kk < 8; ++kk) {
    int c0 = kk * 32 + lg * 8;
    s16x8 af = *(const s16x8*)(arow + c0);
    s16x8 bf = *(const s16x8*)(brow + c0);
    acc = __builtin_amdgcn_mfma_f32_16x16x32_bf16(af, bf, acc, 0, 0, 0);
  }
  int c0 = ot * 16 + lg * 4;
  int t = tt * 16 + l15;
#pragma unroll
  for (int r = 0; r < 4; ++r) {
    int c = c0 + r;
    size_t idx = ((size_t)b * NC + c) * NT + t;
    out[idx] = acc[r] + proj_b[c] + x[idx];
  }
}

extern "C" void kernel_launch(void* const* d_in, const int* in_sizes, int n_in,
                              void* d_out, int out_size, void* d_ws, size_t ws_size,
                              hipStream_t stream) {
  const float* x      = (const float*)d_in[0];
  const float* gw     = (const float*)d_in[1];
  const float* gb     = (const float*)d_in[2];
  const float* qkv_w  = (const float*)d_in[3];
  const float* qkv_b  = (const float*)d_in[4];
  const float* proj_w = (const float*)d_in[5];
  const float* proj_b = (const float*)d_in[6];
  float* out = (float*)d_out;
  char* ws = (char*)d_ws;
  unsigned short* xnT = (unsigned short*)(ws);                 // 8 MiB [B][T][C]
  unsigned short* aT  = (unsigned short*)(ws);                 // reuse (xnT dead after k_qkv)
  unsigned short* qT  = (unsigned short*)(ws + (8u  << 20));   // [BH][T][D]
  unsigned short* kT  = (unsigned short*)(ws + (16u << 20));   // [BH][T][D]
  unsigned short* vS  = (unsigned short*)(ws + (24u << 20));   // [BH][D][T]
  unsigned short* wqb = (unsigned short*)(ws + (32u << 20));
  unsigned short* wpb = (unsigned short*)(ws + (32u << 20) + 768 * 256 * 2);

  hipLaunchKernelGGL(k_cvt_w, dim3(768), dim3(256), 0, stream, qkv_w, proj_w, wqb, wpb);
  hipLaunchKernelGGL(k_gn, dim3(128), dim3(256), 0, stream, x, gw, gb, xnT);
  hipLaunchKernelGGL(k_qkv, dim3(12288), dim3(256), 0, stream, wqb, qkv_b, xnT, qT, kT, vS);
  hipLaunchKernelGGL(k_attn, dim3(512), dim3(256), 0, stream, qT, kT, vS, aT);
  hipLaunchKernelGGL(k_proj, dim3(4096), dim3(256), 0, stream, wpb, proj_b, aT, x, out);
}